// Round 1
// baseline (340.903 us; speedup 1.0000x reference)
//
#include <hip/hip_runtime.h>
#include <hip/hip_bf16.h>

// ---------------------------------------------------------------------------
// MHSA forward: x[2,2048,1024] fp32, Wq/Wk/Wv/Wo [1024,1024] fp32 (Linear: x@W^T)
// out [2,2048,1024] fp32.  Internal compute in bf16 MFMA (threshold is bf16-level).
//
// ws layout (shorts = bf16 bits): Q[4096*1024] K[...] V[...] attn_out[...]
//   = 4 * 8 MiB = 32 MiB required.
// ---------------------------------------------------------------------------

#define DEVI __device__ __forceinline__

typedef __bf16 bf16x8 __attribute__((ext_vector_type(8)));
typedef short  short8 __attribute__((ext_vector_type(8)));
typedef float  f32x4  __attribute__((ext_vector_type(4)));

DEVI short f2bfs(float f) {
    __hip_bfloat16 h = __float2bfloat16(f);
    return __builtin_bit_cast(short, h);
}
DEVI bf16x8 ld8(const short* p) {
    return __builtin_bit_cast(bf16x8, *(const short8*)p);
}

// ---------------------------------------------------------------------------
// NT GEMM: C[M][N] = A[M][K] * B[N][K]^T    (both row-major, inner product over K)
// 128x128 tile, BK=32, 4 waves (2x2), each wave 64x64 = 4x4 fragments of 16x16.
// LDS pad +8 bf16 (stride 80B = 5*16B: keeps b128 alignment, 2-way conflicts only).
// ---------------------------------------------------------------------------
template <bool A_F32, bool B_F32, bool OUT_BF16>
__global__ __launch_bounds__(256) void gemm_nt_kernel(
    const void* __restrict__ Ap, const void* __restrict__ Bp,
    void* __restrict__ Cp, int M, int N, int K) {
    __shared__ short As[128][40];
    __shared__ short Bs[128][40];

    const int tid  = threadIdx.x;
    const int lane = tid & 63;
    const int wid  = tid >> 6;
    const int wm   = wid >> 1, wn = wid & 1;
    const int l15  = lane & 15, l4 = lane >> 4;
    const int row0 = blockIdx.x * 128, col0 = blockIdx.y * 128;

    const int sr = tid >> 1;          // staging row 0..127
    const int sc = (tid & 1) * 16;    // staging col {0,16}

    f32x4 acc[4][4] = {};

    for (int k0 = 0; k0 < K; k0 += 32) {
        __syncthreads();
        // ---- stage A tile ----
        {
            short* dst = &As[sr][sc];
            if (A_F32) {
                const float* g = (const float*)Ap + (size_t)(row0 + sr) * K + k0 + sc;
                const float4* g4 = (const float4*)g;
                float4 w0 = g4[0], w1 = g4[1], w2 = g4[2], w3 = g4[3];
                short8 t0, t1;
                t0[0]=f2bfs(w0.x); t0[1]=f2bfs(w0.y); t0[2]=f2bfs(w0.z); t0[3]=f2bfs(w0.w);
                t0[4]=f2bfs(w1.x); t0[5]=f2bfs(w1.y); t0[6]=f2bfs(w1.z); t0[7]=f2bfs(w1.w);
                t1[0]=f2bfs(w2.x); t1[1]=f2bfs(w2.y); t1[2]=f2bfs(w2.z); t1[3]=f2bfs(w2.w);
                t1[4]=f2bfs(w3.x); t1[5]=f2bfs(w3.y); t1[6]=f2bfs(w3.z); t1[7]=f2bfs(w3.w);
                *(short8*)dst = t0; *(short8*)(dst + 8) = t1;
            } else {
                const short* g = (const short*)Ap + (size_t)(row0 + sr) * K + k0 + sc;
                *(short8*)dst       = *(const short8*)g;
                *(short8*)(dst + 8) = *(const short8*)(g + 8);
            }
        }
        // ---- stage B tile ----
        {
            short* dst = &Bs[sr][sc];
            if (B_F32) {
                const float* g = (const float*)Bp + (size_t)(col0 + sr) * K + k0 + sc;
                const float4* g4 = (const float4*)g;
                float4 w0 = g4[0], w1 = g4[1], w2 = g4[2], w3 = g4[3];
                short8 t0, t1;
                t0[0]=f2bfs(w0.x); t0[1]=f2bfs(w0.y); t0[2]=f2bfs(w0.z); t0[3]=f2bfs(w0.w);
                t0[4]=f2bfs(w1.x); t0[5]=f2bfs(w1.y); t0[6]=f2bfs(w1.z); t0[7]=f2bfs(w1.w);
                t1[0]=f2bfs(w2.x); t1[1]=f2bfs(w2.y); t1[2]=f2bfs(w2.z); t1[3]=f2bfs(w2.w);
                t1[4]=f2bfs(w3.x); t1[5]=f2bfs(w3.y); t1[6]=f2bfs(w3.z); t1[7]=f2bfs(w3.w);
                *(short8*)dst = t0; *(short8*)(dst + 8) = t1;
            } else {
                const short* g = (const short*)Bp + (size_t)(col0 + sr) * K + k0 + sc;
                *(short8*)dst       = *(const short8*)g;
                *(short8*)(dst + 8) = *(const short8*)(g + 8);
            }
        }
        __syncthreads();

        // ---- fragments + MFMA ----
        bf16x8 af[4], bfv[4];
#pragma unroll
        for (int m = 0; m < 4; ++m)
            af[m] = ld8(&As[wm * 64 + m * 16 + l15][l4 * 8]);
#pragma unroll
        for (int n = 0; n < 4; ++n)
            bfv[n] = ld8(&Bs[wn * 64 + n * 16 + l15][l4 * 8]);
#pragma unroll
        for (int m = 0; m < 4; ++m)
#pragma unroll
            for (int n = 0; n < 4; ++n)
                acc[m][n] = __builtin_amdgcn_mfma_f32_16x16x32_bf16(af[m], bfv[n], acc[m][n], 0, 0, 0);
    }

    // ---- epilogue: D col = lane&15, row = (lane>>4)*4 + j  (m89-verified) ----
#pragma unroll
    for (int m = 0; m < 4; ++m)
#pragma unroll
        for (int n = 0; n < 4; ++n)
#pragma unroll
            for (int j = 0; j < 4; ++j) {
                int row = row0 + wm * 64 + m * 16 + l4 * 4 + j;
                int col = col0 + wn * 64 + n * 16 + l15;
                float v = acc[m][n][j];
                if (OUT_BF16) ((short*)Cp)[(size_t)row * N + col] = f2bfs(v);
                else          ((float*)Cp)[(size_t)row * N + col] = v;
            }
}

// ---------------------------------------------------------------------------
// Causal flash attention.  Q,K,V,O: bf16 [4096][1024] (row = b*2048+s, col = h*64+d).
// grid = (s/128, b*h) = (16, 32); block = 256 (4 waves, 32 q-rows each).
// KV tile = 64 rows.  Online softmax wave-parallel over 16 lanes per row.
// ---------------------------------------------------------------------------
__global__ __launch_bounds__(256) void attn_kernel(
    const short* __restrict__ Q, const short* __restrict__ K,
    const short* __restrict__ V, short* __restrict__ O) {
    __shared__ short Ks[64][72];        // K rows, +8 pad (stride 144B = 9*16B)
    __shared__ short Vt[64][72];        // V transposed: Vt[d][kv]
    __shared__ short Ps[4][32][72];     // per-wave P re-layout buffer

    const int tid = threadIdx.x, lane = tid & 63, wid = tid >> 6;
    const int l15 = lane & 15, l4 = lane >> 4;
    const int qt = blockIdx.x, bh = blockIdx.y;
    const int b = bh >> 4, h = bh & 15;
    const size_t base = (size_t)b * 2048 * 1024 + (size_t)h * 64;
    const short* Qp = Q + base;
    const short* Kp = K + base;
    const short* Vp = V + base;
    short* Op = O + base;

    const int q0 = qt * 128 + wid * 32;

    // Q fragments held in registers: rows q0..q0+31, d = 0..63 (2 K-slices)
    bf16x8 qf[2][2];
#pragma unroll
    for (int m = 0; m < 2; ++m)
#pragma unroll
        for (int kk = 0; kk < 2; ++kk)
            qf[m][kk] = ld8(Qp + (size_t)(q0 + m * 16 + l15) * 1024 + kk * 32 + l4 * 8);

    f32x4 o[2][4] = {};
    float mrun[2][4], lrun[2][4];
#pragma unroll
    for (int m = 0; m < 2; ++m)
#pragma unroll
        for (int j = 0; j < 4; ++j) { mrun[m][j] = -INFINITY; lrun[m][j] = 0.f; }

    const int ntiles = 2 * qt + 2;
    for (int t = 0; t < ntiles; ++t) {
        const int kv0 = t * 64;
        __syncthreads();
        // ---- stage K (row-major) and V (transposed) ----
        {
            const int rr0 = tid >> 3;            // 0..31
            const int cc  = (tid & 7) * 8;       // 0..56
#pragma unroll
            for (int i = 0; i < 2; ++i) {
                int rr = rr0 + i * 32;
                *(short8*)&Ks[rr][cc] = *(const short8*)(Kp + (size_t)(kv0 + rr) * 1024 + cc);
                short8 vv = *(const short8*)(Vp + (size_t)(kv0 + rr) * 1024 + cc);
#pragma unroll
                for (int j = 0; j < 8; ++j) Vt[cc + j][rr] = vv[j];
            }
        }
        __syncthreads();

        // ---- S = Q K^T  (32 x 64 per wave) ----
        f32x4 s[2][4] = {};
#pragma unroll
        for (int kk = 0; kk < 2; ++kk) {
            bf16x8 kf[4];
#pragma unroll
            for (int n = 0; n < 4; ++n)
                kf[n] = ld8(&Ks[n * 16 + l15][kk * 32 + l4 * 8]);
#pragma unroll
            for (int m = 0; m < 2; ++m)
#pragma unroll
                for (int n = 0; n < 4; ++n)
                    s[m][n] = __builtin_amdgcn_mfma_f32_16x16x32_bf16(qf[m][kk], kf[n], s[m][n], 0, 0, 0);
        }

        // ---- scale + causal mask + online softmax; write P (bf16) to LDS ----
#pragma unroll
        for (int m = 0; m < 2; ++m) {
            const int qrow_base = q0 + m * 16 + l4 * 4;
#pragma unroll
            for (int j = 0; j < 4; ++j) {
                const int qrow = qrow_base + j;
                float sv[4];
                float rmax = -INFINITY;
#pragma unroll
                for (int n = 0; n < 4; ++n) {
                    int kvc = kv0 + n * 16 + l15;
                    float v = s[m][n][j] * 0.125f;
                    if (kvc > qrow) v = -INFINITY;
                    sv[n] = v;
                    rmax = fmaxf(rmax, v);
                }
#pragma unroll
                for (int off = 1; off < 16; off <<= 1)
                    rmax = fmaxf(rmax, __shfl_xor(rmax, off, 64));
                float mold = mrun[m][j];
                float mnew = fmaxf(mold, rmax);
                float corr = __expf(mold - mnew);   // exp(-inf)=0 on first tile
                float rsum = 0.f;
#pragma unroll
                for (int n = 0; n < 4; ++n) {
                    float p = __expf(sv[n] - mnew);  // masked -> 0
                    rsum += p;
                    Ps[wid][m * 16 + l4 * 4 + j][n * 16 + l15] = f2bfs(p);
                }
#pragma unroll
                for (int off = 1; off < 16; off <<= 1)
                    rsum += __shfl_xor(rsum, off, 64);
                mrun[m][j] = mnew;
                lrun[m][j] = lrun[m][j] * corr + rsum;
#pragma unroll
                for (int n = 0; n < 4; ++n) o[m][n][j] *= corr;
            }
        }
        __syncthreads();   // P writes -> P reads (and keeps Vt stable)

        // ---- O += P V  (P: 32x64 A-frags from LDS, V^T: B-frags from Vt) ----
#pragma unroll
        for (int kk = 0; kk < 2; ++kk) {
            bf16x8 pa[2], vb[4];
#pragma unroll
            for (int m = 0; m < 2; ++m)
                pa[m] = ld8(&Ps[wid][m * 16 + l15][kk * 32 + l4 * 8]);
#pragma unroll
            for (int n = 0; n < 4; ++n)
                vb[n] = ld8(&Vt[n * 16 + l15][kk * 32 + l4 * 8]);
#pragma unroll
            for (int m = 0; m < 2; ++m)
#pragma unroll
                for (int n = 0; n < 4; ++n)
                    o[m][n] = __builtin_amdgcn_mfma_f32_16x16x32_bf16(pa[m], vb[n], o[m][n], 0, 0, 0);
        }
    }

    // ---- epilogue: O / l ----
#pragma unroll
    for (int m = 0; m < 2; ++m)
#pragma unroll
        for (int j = 0; j < 4; ++j) {
            float inv = 1.0f / lrun[m][j];
            int row = q0 + m * 16 + l4 * 4 + j;
#pragma unroll
            for (int n = 0; n < 4; ++n)
                Op[(size_t)row * 1024 + n * 16 + l15] = f2bfs(o[m][n][j] * inv);
        }
}

// ---------------------------------------------------------------------------
extern "C" void kernel_launch(void* const* d_in, const int* in_sizes, int n_in,
                              void* d_out, int out_size, void* d_ws, size_t ws_size,
                              hipStream_t stream) {
    const float* x  = (const float*)d_in[0];
    const float* Wq = (const float*)d_in[1];
    const float* Wk = (const float*)d_in[2];
    const float* Wv = (const float*)d_in[3];
    const float* Wo = (const float*)d_in[4];
    float* out = (float*)d_out;

    const size_t NTOK = (size_t)4096 * 1024;
    short* Qw = (short*)d_ws;          // 8 MiB each, 32 MiB total
    short* Kw = Qw + NTOK;
    short* Vw = Kw + NTOK;
    short* Aw = Vw + NTOK;

    dim3 gg(32, 8);   // M/128 x N/128
    dim3 gb(256);

    gemm_nt_kernel<true, true, true><<<gg, gb, 0, stream>>>(x, Wq, Qw, 4096, 1024, 1024);
    gemm_nt_kernel<true, true, true><<<gg, gb, 0, stream>>>(x, Wk, Kw, 4096, 1024, 1024);
    gemm_nt_kernel<true, true, true><<<gg, gb, 0, stream>>>(x, Wv, Vw, 4096, 1024, 1024);

    attn_kernel<<<dim3(16, 32), gb, 0, stream>>>(Qw, Kw, Vw, Aw);

    gemm_nt_kernel<false, true, false><<<gg, gb, 0, stream>>>(Aw, Wo, out, 4096, 1024, 1024);
}

// Round 2
// 207.927 us; speedup vs baseline: 1.6395x; 1.6395x over previous
//
#include <hip/hip_runtime.h>
#include <hip/hip_bf16.h>

// ---------------------------------------------------------------------------
// MHSA: x[2,2048,1024] f32, Wq/Wk/Wv/Wo[1024,1024] f32 -> out[2,2048,1024] f32.
// Internal bf16. Pipeline:
//   1) convert: x -> xb (bf16, stored in d_out[0:8MB]); W* -> wb (ws)
//   2) fused QKV GEMM (global_load_lds staging): Q,K row-major; V transposed
//      (VtG[1024][4096]) written directly from the epilogue
//   3) causal flash attention, heavy-tile-first schedule, O overwrites Q buf
//   4) Wo GEMM -> f32 d_out
// ws (shorts): wb[4x1M] Q[4M] K[4M] VtG[4M] = 32 MB. attn out aliases Q.
// ---------------------------------------------------------------------------

#define DEVI __device__ __forceinline__

typedef __bf16 bf16x8 __attribute__((ext_vector_type(8)));
typedef short  short8 __attribute__((ext_vector_type(8)));
typedef float  f32x4  __attribute__((ext_vector_type(4)));

DEVI short f2bfs(float f) {
    __hip_bfloat16 h = __float2bfloat16(f);
    return __builtin_bit_cast(short, h);
}
DEVI bf16x8 ld8(const short* p) {
    return __builtin_bit_cast(bf16x8, *(const short8*)p);
}
DEVI void gload16(const void* g, void* lds) {
    __builtin_amdgcn_global_load_lds(
        (const __attribute__((address_space(1))) void*)g,
        (__attribute__((address_space(3))) void*)lds, 16, 0, 0);
}

// ---------------------------------------------------------------------------
// f32 -> bf16 convert.  z=0: x (4M elems) -> xb; z=1..4: W* (1M) -> wb slots.
// ---------------------------------------------------------------------------
__global__ __launch_bounds__(256) void convert_kernel(
    const float* __restrict__ x, const float* __restrict__ Wq,
    const float* __restrict__ Wk, const float* __restrict__ Wv,
    const float* __restrict__ Wo, short* __restrict__ xb, short* __restrict__ wb) {
    const int z = blockIdx.y;
    const float* src;
    short* dst;
    int n;
    if (z == 0) { src = x; dst = xb; n = 4194304; }
    else {
        src = (z == 1) ? Wq : (z == 2) ? Wk : (z == 3) ? Wv : Wo;
        dst = wb + (size_t)(z - 1) * 1048576;
        n = 1048576;
    }
    const int i8 = (blockIdx.x * 256 + threadIdx.x) * 8;
    if (i8 >= n) return;
    float4 a = ((const float4*)(src + i8))[0];
    float4 b = ((const float4*)(src + i8))[1];
    short8 t;
    t[0] = f2bfs(a.x); t[1] = f2bfs(a.y); t[2] = f2bfs(a.z); t[3] = f2bfs(a.w);
    t[4] = f2bfs(b.x); t[5] = f2bfs(b.y); t[6] = f2bfs(b.z); t[7] = f2bfs(b.w);
    *(short8*)(dst + i8) = t;
}

// ---------------------------------------------------------------------------
// Shared bf16 NT-GEMM K-loop (m97 structure): 128x128 tile, BK=32,
// global_load_lds width-16 staging into linear LDS, 16 MFMA / K-step.
// A, B point at the tile origin rows (row stride 1024).
// ---------------------------------------------------------------------------
DEVI void gemm_kloop(const short* __restrict__ A, const short* __restrict__ B,
                     short* As, short* Bs, int wid, int lane, f32x4 acc[4][4]) {
    const int l15 = lane & 15, l4 = lane >> 4;
    const int wm = wid >> 1, wn = wid & 1;
    const int crow = lane >> 2;          // row within 16-row chunk-block
    const int ccol = (lane & 3) * 8;     // col in shorts
#pragma unroll 1
    for (int k0 = 0; k0 < 1024; k0 += 32) {
        __syncthreads();
#pragma unroll
        for (int i = 0; i < 2; ++i) {
            const int cb = wid * 2 + i;  // 0..7, 16 rows each
            gload16(A + (size_t)(cb * 16 + crow) * 1024 + k0 + ccol, As + cb * 512);
            gload16(B + (size_t)(cb * 16 + crow) * 1024 + k0 + ccol, Bs + cb * 512);
        }
        __syncthreads();
        bf16x8 af[4], bfv[4];
#pragma unroll
        for (int m = 0; m < 4; ++m)
            af[m] = ld8(As + (wm * 64 + m * 16 + l15) * 32 + l4 * 8);
#pragma unroll
        for (int n = 0; n < 4; ++n)
            bfv[n] = ld8(Bs + (wn * 64 + n * 16 + l15) * 32 + l4 * 8);
#pragma unroll
        for (int m = 0; m < 4; ++m)
#pragma unroll
            for (int n = 0; n < 4; ++n)
                acc[m][n] = __builtin_amdgcn_mfma_f32_16x16x32_bf16(af[m], bfv[n], acc[m][n], 0, 0, 0);
    }
}

// ---------------------------------------------------------------------------
// Fused QKV projection. grid (32, 24): y>>3 selects weight; (y&7) col tile.
// Q,K: bf16 row-major [4096][1024].  V: transposed VtG[1024][4096].
// ---------------------------------------------------------------------------
__global__ __launch_bounds__(256) void gemm_qkv_kernel(
    const short* __restrict__ xb, const short* __restrict__ wb,
    short* __restrict__ Qo, short* __restrict__ Ko, short* __restrict__ VtG) {
    __shared__ short As[4096], Bs[4096];
    const int tid = threadIdx.x, lane = tid & 63, wid = tid >> 6;
    const int l15 = lane & 15, l4 = lane >> 4;
    const int wm = wid >> 1, wn = wid & 1;
    const int y = blockIdx.y, wsel = y >> 3;
    const int row0 = blockIdx.x * 128, col0 = (y & 7) * 128;

    f32x4 acc[4][4] = {};
    gemm_kloop(xb + (size_t)row0 * 1024,
               wb + (size_t)wsel * 1048576 + (size_t)col0 * 1024,
               As, Bs, wid, lane, acc);

    if (wsel == 2) {
#pragma unroll
        for (int m = 0; m < 4; ++m)
#pragma unroll
            for (int n = 0; n < 4; ++n)
#pragma unroll
                for (int j = 0; j < 4; ++j) {
                    int row = row0 + wm * 64 + m * 16 + l4 * 4 + j;
                    int col = col0 + wn * 64 + n * 16 + l15;
                    VtG[(size_t)col * 4096 + row] = f2bfs(acc[m][n][j]);
                }
    } else {
        short* C = (wsel == 0) ? Qo : Ko;
#pragma unroll
        for (int m = 0; m < 4; ++m)
#pragma unroll
            for (int n = 0; n < 4; ++n)
#pragma unroll
                for (int j = 0; j < 4; ++j) {
                    int row = row0 + wm * 64 + m * 16 + l4 * 4 + j;
                    int col = col0 + wn * 64 + n * 16 + l15;
                    C[(size_t)row * 1024 + col] = f2bfs(acc[m][n][j]);
                }
    }
}

// ---------------------------------------------------------------------------
// Output projection: A = attn out (bf16), B = Wo (bf16), C = f32 d_out.
// ---------------------------------------------------------------------------
__global__ __launch_bounds__(256) void gemm_wo_kernel(
    const short* __restrict__ Ao, const short* __restrict__ Wob,
    float* __restrict__ Cout) {
    __shared__ short As[4096], Bs[4096];
    const int tid = threadIdx.x, lane = tid & 63, wid = tid >> 6;
    const int l15 = lane & 15, l4 = lane >> 4;
    const int wm = wid >> 1, wn = wid & 1;
    const int row0 = blockIdx.x * 128, col0 = blockIdx.y * 128;

    f32x4 acc[4][4] = {};
    gemm_kloop(Ao + (size_t)row0 * 1024, Wob + (size_t)col0 * 1024,
               As, Bs, wid, lane, acc);

#pragma unroll
    for (int m = 0; m < 4; ++m)
#pragma unroll
        for (int n = 0; n < 4; ++n)
#pragma unroll
            for (int j = 0; j < 4; ++j) {
                int row = row0 + wm * 64 + m * 16 + l4 * 4 + j;
                int col = col0 + wn * 64 + n * 16 + l15;
                Cout[(size_t)row * 1024 + col] = acc[m][n][j];
            }
}

// ---------------------------------------------------------------------------
// Causal flash attention. Q,K: bf16 [4096][1024]; V via VtG[1024][4096].
// grid 512 (1-D): qt = 15 - bid/32 (heavy tiles dispatched first), bh = bid&31.
// Block 256 = 4 waves x 32 q-rows. KV tile 64. O overwrites Q rows (safe:
// Q read into regs at start, only this block touches these rows).
// ---------------------------------------------------------------------------
__global__ __launch_bounds__(256) void attn_kernel(
    const short* __restrict__ Q, const short* __restrict__ K,
    const short* __restrict__ VtG, short* __restrict__ O) {
    __shared__ short Ks[64][72];
    __shared__ short Vts[64][72];       // Vts[d][kv]
    __shared__ short Ps[4][32][72];     // per-wave P re-layout

    const int tid = threadIdx.x, lane = tid & 63, wid = tid >> 6;
    const int l15 = lane & 15, l4 = lane >> 4;
    const int bid = blockIdx.x;
    const int qt = 15 - (bid >> 5);
    const int bh = bid & 31;
    const int b = bh >> 4, h = bh & 15;
    const size_t base = (size_t)b * 2048 * 1024 + (size_t)h * 64;
    const short* Qp = Q + base;
    const short* Kp = K + base;
    const short* Vp = VtG + (size_t)(h * 64) * 4096 + (size_t)b * 2048;
    short* Op = O + base;

    const int q0 = qt * 128 + wid * 32;

    bf16x8 qf[2][2];
#pragma unroll
    for (int m = 0; m < 2; ++m)
#pragma unroll
        for (int kk = 0; kk < 2; ++kk)
            qf[m][kk] = ld8(Qp + (size_t)(q0 + m * 16 + l15) * 1024 + kk * 32 + l4 * 8);

    f32x4 o[2][4] = {};
    float mrun[2][4], lrun[2][4];
#pragma unroll
    for (int m = 0; m < 2; ++m)
#pragma unroll
        for (int j = 0; j < 4; ++j) { mrun[m][j] = -INFINITY; lrun[m][j] = 0.f; }

    const int ntiles = 2 * qt + 2;
    const int srr = tid >> 3, scc = (tid & 7) * 8;
    for (int t = 0; t < ntiles; ++t) {
        const int kv0 = t * 64;
        __syncthreads();
        // ---- stage K rows + Vt rows (both vectorized b128, pad-72) ----
#pragma unroll
        for (int i = 0; i < 2; ++i) {
            const int rr = srr + i * 32;
            *(short8*)&Ks[rr][scc]  = *(const short8*)(Kp + (size_t)(kv0 + rr) * 1024 + scc);
            *(short8*)&Vts[rr][scc] = *(const short8*)(Vp + (size_t)rr * 4096 + kv0 + scc);
        }
        __syncthreads();

        // ---- S = Q K^T ----
        f32x4 s[2][4] = {};
        __builtin_amdgcn_s_setprio(1);
#pragma unroll
        for (int kk = 0; kk < 2; ++kk) {
            bf16x8 kf[4];
#pragma unroll
            for (int n = 0; n < 4; ++n)
                kf[n] = ld8(&Ks[n * 16 + l15][kk * 32 + l4 * 8]);
#pragma unroll
            for (int m = 0; m < 2; ++m)
#pragma unroll
                for (int n = 0; n < 4; ++n)
                    s[m][n] = __builtin_amdgcn_mfma_f32_16x16x32_bf16(qf[m][kk], kf[n], s[m][n], 0, 0, 0);
        }
        __builtin_amdgcn_s_setprio(0);

        // ---- softmax (online); mask only on diagonal tiles ----
        const bool need_mask = (kv0 + 63 > q0);   // wave-uniform
#pragma unroll
        for (int m = 0; m < 2; ++m) {
            const int rloc = m * 16 + l4 * 4;
#pragma unroll
            for (int j = 0; j < 4; ++j) {
                const int qrow = q0 + rloc + j;
                float sv[4];
                float rmax = -INFINITY;
                if (need_mask) {
#pragma unroll
                    for (int n = 0; n < 4; ++n) {
                        int kvc = kv0 + n * 16 + l15;
                        float v = s[m][n][j] * 0.125f;
                        if (kvc > qrow) v = -INFINITY;
                        sv[n] = v;
                        rmax = fmaxf(rmax, v);
                    }
                } else {
#pragma unroll
                    for (int n = 0; n < 4; ++n) {
                        float v = s[m][n][j] * 0.125f;
                        sv[n] = v;
                        rmax = fmaxf(rmax, v);
                    }
                }
#pragma unroll
                for (int off = 1; off < 16; off <<= 1)
                    rmax = fmaxf(rmax, __shfl_xor(rmax, off, 64));
                const float mold = mrun[m][j];
                const float mnew = fmaxf(mold, rmax);
                const float corr = __expf(mold - mnew);
                float rsum = 0.f;
#pragma unroll
                for (int n = 0; n < 4; ++n) {
                    float p = __expf(sv[n] - mnew);
                    rsum += p;
                    Ps[wid][rloc + j][n * 16 + l15] = f2bfs(p);
                }
#pragma unroll
                for (int off = 1; off < 16; off <<= 1)
                    rsum += __shfl_xor(rsum, off, 64);
                mrun[m][j] = mnew;
                lrun[m][j] = lrun[m][j] * corr + rsum;
#pragma unroll
                for (int n = 0; n < 4; ++n) o[m][n][j] *= corr;
            }
        }
        // Ps is per-wave: no barrier needed, but keep the compiler from
        // reordering the ds_reads above the ds_writes (HW DS is in-order).
        asm volatile("" ::: "memory");

        // ---- O += P V ----
        __builtin_amdgcn_s_setprio(1);
#pragma unroll
        for (int kk = 0; kk < 2; ++kk) {
            bf16x8 pa[2], vb[4];
#pragma unroll
            for (int m = 0; m < 2; ++m)
                pa[m] = ld8(&Ps[wid][m * 16 + l15][kk * 32 + l4 * 8]);
#pragma unroll
            for (int n = 0; n < 4; ++n)
                vb[n] = ld8(&Vts[n * 16 + l15][kk * 32 + l4 * 8]);
#pragma unroll
            for (int m = 0; m < 2; ++m)
#pragma unroll
                for (int n = 0; n < 4; ++n)
                    o[m][n] = __builtin_amdgcn_mfma_f32_16x16x32_bf16(pa[m], vb[n], o[m][n], 0, 0, 0);
        }
        __builtin_amdgcn_s_setprio(0);
    }

    // ---- epilogue ----
#pragma unroll
    for (int m = 0; m < 2; ++m)
#pragma unroll
        for (int j = 0; j < 4; ++j) {
            const float inv = 1.0f / lrun[m][j];
            const int row = q0 + m * 16 + l4 * 4 + j;
#pragma unroll
            for (int n = 0; n < 4; ++n)
                Op[(size_t)row * 1024 + n * 16 + l15] = f2bfs(o[m][n][j] * inv);
        }
}

// ---------------------------------------------------------------------------
extern "C" void kernel_launch(void* const* d_in, const int* in_sizes, int n_in,
                              void* d_out, int out_size, void* d_ws, size_t ws_size,
                              hipStream_t stream) {
    const float* x  = (const float*)d_in[0];
    const float* Wq = (const float*)d_in[1];
    const float* Wk = (const float*)d_in[2];
    const float* Wv = (const float*)d_in[3];
    const float* Wo = (const float*)d_in[4];

    short* wb  = (short*)d_ws;                 // 4 x 1M shorts (8 MB)
    short* Qw  = wb + (size_t)4 * 1048576;     // 8 MB (attn out aliases this)
    short* Kw  = Qw + (size_t)4194304;         // 8 MB
    short* Vtw = Kw + (size_t)4194304;         // 8 MB  (VtG[1024][4096])
    short* xb  = (short*)d_out;                // bf16 x lives in d_out[0:8MB]

    convert_kernel<<<dim3(2048, 5), 256, 0, stream>>>(x, Wq, Wk, Wv, Wo, xb, wb);
    gemm_qkv_kernel<<<dim3(32, 24), 256, 0, stream>>>(xb, wb, Qw, Kw, Vtw);
    attn_kernel<<<512, 256, 0, stream>>>(Qw, Kw, Vtw, Qw);
    gemm_wo_kernel<<<dim3(32, 8), 256, 0, stream>>>(Qw, wb + (size_t)3 * 1048576, (float*)d_out);
}

// Round 4
// 158.123 us; speedup vs baseline: 2.1559x; 1.3150x over previous
//
#include <hip/hip_runtime.h>
#include <hip/hip_bf16.h>

// ---------------------------------------------------------------------------
// MHSA: x[2,2048,1024] f32, Wq/Wk/Wv/Wo[1024,1024] f32 -> out[2,2048,1024] f32.
// Internal bf16. Pipeline:
//   1) convert: x -> xb (bf16 in d_out[0:8MB]); W* -> wb (ws)
//   2) fused QKV GEMM (global_load_lds): Q,K row-major; V transposed VtG[1024][4096]
//   3) causal flash attention, swapped-QK^T 32x32 MFMA, in-register softmax
//   4) Wo GEMM -> f32 d_out
// ws (shorts): wb[4x1M] Q[4M] K[4M] VtG[4M] = 32 MB. attn out aliases Q.
// ---------------------------------------------------------------------------

#define DEVI __device__ __forceinline__

typedef __bf16 bf16x8 __attribute__((ext_vector_type(8)));
typedef short  short8 __attribute__((ext_vector_type(8)));
typedef float  f32x4  __attribute__((ext_vector_type(4)));
typedef float  f32x16 __attribute__((ext_vector_type(16)));
typedef unsigned int u32x4 __attribute__((ext_vector_type(4)));

DEVI short f2bfs(float f) {
    __hip_bfloat16 h = __float2bfloat16(f);
    return __builtin_bit_cast(short, h);
}
DEVI unsigned pack2(float a, float b) {
    return (unsigned)(unsigned short)f2bfs(a) | ((unsigned)(unsigned short)f2bfs(b) << 16);
}
DEVI bf16x8 ld8(const short* p) {
    return __builtin_bit_cast(bf16x8, *(const short8*)p);
}
DEVI void gload16(const void* g, void* lds) {
    __builtin_amdgcn_global_load_lds(
        (const __attribute__((address_space(1))) void*)g,
        (__attribute__((address_space(3))) void*)lds, 16, 0, 0);
}
// XOR-swizzled LDS address for [64][64] bf16 tiles: conflict-free for both
// row-staged b128 writes and column-slice b128 reads (G4 pattern).
DEVI short* lds_sw(short* base, int row, int col) {
    return (short*)((char*)base + (((row << 7) + (col << 1)) ^ ((row & 7) << 4)));
}

// ---------------------------------------------------------------------------
// f32 -> bf16 convert.  z=0: x (4M elems) -> xb; z=1..4: W* (1M) -> wb slots.
// ---------------------------------------------------------------------------
__global__ __launch_bounds__(256) void convert_kernel(
    const float* __restrict__ x, const float* __restrict__ Wq,
    const float* __restrict__ Wk, const float* __restrict__ Wv,
    const float* __restrict__ Wo, short* __restrict__ xb, short* __restrict__ wb) {
    const int z = blockIdx.y;
    const float* src;
    short* dst;
    int n;
    if (z == 0) { src = x; dst = xb; n = 4194304; }
    else {
        src = (z == 1) ? Wq : (z == 2) ? Wk : (z == 3) ? Wv : Wo;
        dst = wb + (size_t)(z - 1) * 1048576;
        n = 1048576;
    }
    const int i8 = (blockIdx.x * 256 + threadIdx.x) * 8;
    if (i8 >= n) return;
    float4 a = ((const float4*)(src + i8))[0];
    float4 b = ((const float4*)(src + i8))[1];
    short8 t;
    t[0] = f2bfs(a.x); t[1] = f2bfs(a.y); t[2] = f2bfs(a.z); t[3] = f2bfs(a.w);
    t[4] = f2bfs(b.x); t[5] = f2bfs(b.y); t[6] = f2bfs(b.z); t[7] = f2bfs(b.w);
    *(short8*)(dst + i8) = t;
}

// ---------------------------------------------------------------------------
// bf16 NT-GEMM K-loop (m97 structure): 128x128 tile, BK=32, global_load_lds.
// ---------------------------------------------------------------------------
DEVI void gemm_kloop(const short* __restrict__ A, const short* __restrict__ B,
                     short* As, short* Bs, int wid, int lane, f32x4 acc[4][4]) {
    const int l15 = lane & 15, l4 = lane >> 4;
    const int wm = wid >> 1, wn = wid & 1;
    const int crow = lane >> 2;
    const int ccol = (lane & 3) * 8;
#pragma unroll 1
    for (int k0 = 0; k0 < 1024; k0 += 32) {
        __syncthreads();
#pragma unroll
        for (int i = 0; i < 2; ++i) {
            const int cb = wid * 2 + i;
            gload16(A + (size_t)(cb * 16 + crow) * 1024 + k0 + ccol, As + cb * 512);
            gload16(B + (size_t)(cb * 16 + crow) * 1024 + k0 + ccol, Bs + cb * 512);
        }
        __syncthreads();
        bf16x8 af[4], bfv[4];
#pragma unroll
        for (int m = 0; m < 4; ++m)
            af[m] = ld8(As + (wm * 64 + m * 16 + l15) * 32 + l4 * 8);
#pragma unroll
        for (int n = 0; n < 4; ++n)
            bfv[n] = ld8(Bs + (wn * 64 + n * 16 + l15) * 32 + l4 * 8);
#pragma unroll
        for (int m = 0; m < 4; ++m)
#pragma unroll
            for (int n = 0; n < 4; ++n)
                acc[m][n] = __builtin_amdgcn_mfma_f32_16x16x32_bf16(af[m], bfv[n], acc[m][n], 0, 0, 0);
    }
}

// ---------------------------------------------------------------------------
// Fused QKV projection. grid (32, 24): y>>3 selects weight; (y&7) col tile.
// ---------------------------------------------------------------------------
__global__ __launch_bounds__(256) void gemm_qkv_kernel(
    const short* __restrict__ xb, const short* __restrict__ wb,
    short* __restrict__ Qo, short* __restrict__ Ko, short* __restrict__ VtG) {
    __shared__ short As[4096], Bs[4096];
    const int tid = threadIdx.x, lane = tid & 63, wid = tid >> 6;
    const int l15 = lane & 15, l4 = lane >> 4;
    const int wm = wid >> 1, wn = wid & 1;
    const int y = blockIdx.y, wsel = y >> 3;
    const int row0 = blockIdx.x * 128, col0 = (y & 7) * 128;

    f32x4 acc[4][4] = {};
    gemm_kloop(xb + (size_t)row0 * 1024,
               wb + (size_t)wsel * 1048576 + (size_t)col0 * 1024,
               As, Bs, wid, lane, acc);

    if (wsel == 2) {
#pragma unroll
        for (int m = 0; m < 4; ++m)
#pragma unroll
            for (int n = 0; n < 4; ++n)
#pragma unroll
                for (int j = 0; j < 4; ++j) {
                    int row = row0 + wm * 64 + m * 16 + l4 * 4 + j;
                    int col = col0 + wn * 64 + n * 16 + l15;
                    VtG[(size_t)col * 4096 + row] = f2bfs(acc[m][n][j]);
                }
    } else {
        short* C = (wsel == 0) ? Qo : Ko;
#pragma unroll
        for (int m = 0; m < 4; ++m)
#pragma unroll
            for (int n = 0; n < 4; ++n)
#pragma unroll
                for (int j = 0; j < 4; ++j) {
                    int row = row0 + wm * 64 + m * 16 + l4 * 4 + j;
                    int col = col0 + wn * 64 + n * 16 + l15;
                    C[(size_t)row * 1024 + col] = f2bfs(acc[m][n][j]);
                }
    }
}

__global__ __launch_bounds__(256) void gemm_wo_kernel(
    const short* __restrict__ Ao, const short* __restrict__ Wob,
    float* __restrict__ Cout) {
    __shared__ short As[4096], Bs[4096];
    const int tid = threadIdx.x, lane = tid & 63, wid = tid >> 6;
    const int l15 = lane & 15, l4 = lane >> 4;
    const int wm = wid >> 1, wn = wid & 1;
    const int row0 = blockIdx.x * 128, col0 = blockIdx.y * 128;

    f32x4 acc[4][4] = {};
    gemm_kloop(Ao + (size_t)row0 * 1024, Wob + (size_t)col0 * 1024,
               As, Bs, wid, lane, acc);

#pragma unroll
    for (int m = 0; m < 4; ++m)
#pragma unroll
        for (int n = 0; n < 4; ++n)
#pragma unroll
            for (int j = 0; j < 4; ++j) {
                int row = row0 + wm * 64 + m * 16 + l4 * 4 + j;
                int col = col0 + wn * 64 + n * 16 + l15;
                Cout[(size_t)row * 1024 + col] = acc[m][n][j];
            }
}

// ---------------------------------------------------------------------------
// Causal flash attention, swapped-QK^T 32x32x16 MFMA, in-register softmax.
// grid 1024 (1-D, heavy-first): qt = 31 - bid/32, bh = bid&31.
// block 128 = 2 warps x 32 q-rows. KV tile 64.
// Each lane owns q-row = q0w + (lane&31); S rows (kv) live in regs:
//   C row = (reg&3) + 8*(reg>>2) + 4*(lane>>5), col = lane&31  (m74/m101).
// P redistribution to PV A-frags via pack + shfl_xor(32) (T12 derivation).
// ---------------------------------------------------------------------------
__global__ __launch_bounds__(128) void attn_kernel(
    const short* __restrict__ Q, const short* __restrict__ K,
    const short* __restrict__ VtG, short* __restrict__ O) {
    __shared__ short Ks[4096];          // [64 kv][64 d], XOR-swizzled
    __shared__ short Vts[4096];         // [64 dv][64 kv], XOR-swizzled

    const int tid = threadIdx.x, lane = tid & 63, wid = tid >> 6;
    const int l31 = lane & 31, hi = lane >> 5;
    const int bid = blockIdx.x;
    const int qt = 31 - (bid >> 5);     // heavy tiles dispatched first
    const int bh = bid & 31;
    const int b = bh >> 4, h = bh & 15;
    const size_t base = (size_t)b * 2048 * 1024 + (size_t)h * 64;
    const short* Qp = Q + base;
    const short* Kp = K + base;
    const short* Vp = VtG + (size_t)(h * 64) * 4096 + (size_t)b * 2048;
    short* Op = O + base;

    const int q0w = qt * 64 + wid * 32;
    const int qrow = q0w + l31;          // this lane's q row (per-head)

    // Q B-fragments: qf[ds] = Q[qrow][ds*16 + hi*8 + 0..7]
    bf16x8 qf[4];
#pragma unroll
    for (int ds = 0; ds < 4; ++ds)
        qf[ds] = ld8(Qp + (size_t)qrow * 1024 + ds * 16 + hi * 8);

    f32x16 o0 = 0.0f, o1 = 0.0f;
    float m = -INFINITY, l = 0.0f;

    const int srow = tid >> 3;           // 0..15
    const int scol = (tid & 7) * 8;

    const int ntiles = qt + 1;
    for (int t = 0; t < ntiles; ++t) {
        const int kv0 = t * 64;
        __syncthreads();
        // ---- stage K[kv][d] and Vt[dv][kv], swizzled, b128 ----
#pragma unroll
        for (int i = 0; i < 4; ++i) {
            const int rr = srow + 16 * i;
            *(short8*)lds_sw(Ks, rr, scol) =
                *(const short8*)(Kp + (size_t)(kv0 + rr) * 1024 + scol);
            *(short8*)lds_sw(Vts, rr, scol) =
                *(const short8*)(Vp + (size_t)rr * 4096 + kv0 + scol);
        }
        __syncthreads();

        // ---- S = K Q^T : C[kv][q], 2 chunks of 32 kv ----
        f32x16 s0 = 0.0f, s1 = 0.0f;
        __builtin_amdgcn_s_setprio(1);
#pragma unroll
        for (int ds = 0; ds < 4; ++ds) {
            bf16x8 kf0 = ld8(lds_sw(Ks, l31, ds * 16 + hi * 8));
            s0 = __builtin_amdgcn_mfma_f32_32x32x16_bf16(kf0, qf[ds], s0, 0, 0, 0);
        }
#pragma unroll
        for (int ds = 0; ds < 4; ++ds) {
            bf16x8 kf1 = ld8(lds_sw(Ks, 32 + l31, ds * 16 + hi * 8));
            s1 = __builtin_amdgcn_mfma_f32_32x32x16_bf16(kf1, qf[ds], s1, 0, 0, 0);
        }
        __builtin_amdgcn_s_setprio(0);

        // ---- scale + causal mask + row max (all in-register) ----
        // mask needed iff tile's max kv exceeds the wave's FIRST q row
        const bool diag = (kv0 + 63 > q0w);        // wave-uniform (bugfix)
        float pmax = -3.0e38f;
#pragma unroll
        for (int r = 0; r < 16; ++r) {
            float v0 = s0[r] * 0.125f;
            float v1 = s1[r] * 0.125f;
            if (diag) {
                const int kvr = kv0 + (r & 3) + 8 * (r >> 2) + 4 * hi;
                if (kvr > qrow)      v0 = -3.0e38f;
                if (kvr + 32 > qrow) v1 = -3.0e38f;
            }
            s0[r] = v0; s1[r] = v1;
            pmax = fmaxf(pmax, fmaxf(v0, v1));
        }
        pmax = fmaxf(pmax, __shfl_xor(pmax, 32, 64));

        // ---- defer-max rescale (T13): rare after first tiles ----
        if (__any(pmax > m + 8.0f)) {
            const float mnew = fmaxf(m, pmax);
            const float corr = __expf(m - mnew);
            m = mnew;
            l *= corr;
#pragma unroll
            for (int r = 0; r < 16; ++r) {
                const int cr = (r & 3) + 8 * (r >> 2) + 4 * hi;
                const float c = __shfl(corr, cr, 64);
                o0[r] *= c; o1[r] *= c;
            }
        }

        // ---- P = exp(S - m), pack to bf16 pairs, accumulate l ----
        float rsum = 0.0f;
        unsigned w0[8], w1[8];
#pragma unroll
        for (int i = 0; i < 8; ++i) {
            const float p0 = __expf(s0[2 * i] - m);
            const float p1 = __expf(s0[2 * i + 1] - m);
            const float p2 = __expf(s1[2 * i] - m);
            const float p3 = __expf(s1[2 * i + 1] - m);
            rsum += (p0 + p1) + (p2 + p3);
            w0[i] = pack2(p0, p1);
            w1[i] = pack2(p2, p3);
        }
        l += rsum + __shfl_xor(rsum, 32, 64);

        // ---- redistribute P across lane pairs -> PA frags; O += P V ----
        __builtin_amdgcn_s_setprio(1);
#pragma unroll
        for (int c = 0; c < 2; ++c) {
            const unsigned* w = (c == 0) ? w0 : w1;
            unsigned pw[8];
#pragma unroll
            for (int i = 0; i < 8; ++i) pw[i] = __shfl_xor(w[i], 32, 64);
            u32x4 lo, hiw;
            lo[0]  = hi ? pw[2] : w[0];  lo[1]  = hi ? pw[3] : w[1];
            lo[2]  = hi ? w[2]  : pw[0]; lo[3]  = hi ? w[3]  : pw[1];
            hiw[0] = hi ? pw[6] : w[4];  hiw[1] = hi ? pw[7] : w[5];
            hiw[2] = hi ? w[6]  : pw[4]; hiw[3] = hi ? w[7]  : pw[5];
            const bf16x8 paL = __builtin_bit_cast(bf16x8, lo);
            const bf16x8 paH = __builtin_bit_cast(bf16x8, hiw);

            bf16x8 vb;
            vb = ld8(lds_sw(Vts, l31,      c * 32 + hi * 8));
            o0 = __builtin_amdgcn_mfma_f32_32x32x16_bf16(paL, vb, o0, 0, 0, 0);
            vb = ld8(lds_sw(Vts, 32 + l31, c * 32 + hi * 8));
            o1 = __builtin_amdgcn_mfma_f32_32x32x16_bf16(paL, vb, o1, 0, 0, 0);
            vb = ld8(lds_sw(Vts, l31,      c * 32 + 16 + hi * 8));
            o0 = __builtin_amdgcn_mfma_f32_32x32x16_bf16(paH, vb, o0, 0, 0, 0);
            vb = ld8(lds_sw(Vts, 32 + l31, c * 32 + 16 + hi * 8));
            o1 = __builtin_amdgcn_mfma_f32_32x32x16_bf16(paH, vb, o1, 0, 0, 0);
        }
        __builtin_amdgcn_s_setprio(0);
    }

    // ---- epilogue: O / l, write [q][dv] rows (coalesced per reg) ----
    const float il = 1.0f / l;
#pragma unroll
    for (int r = 0; r < 16; ++r) {
        const int cr = (r & 3) + 8 * (r >> 2) + 4 * hi;
        const float s = __shfl(il, cr, 64);
        const size_t row = (size_t)(q0w + cr) * 1024;
        Op[row + l31]      = f2bfs(o0[r] * s);
        Op[row + 32 + l31] = f2bfs(o1[r] * s);
    }
}

// ---------------------------------------------------------------------------
extern "C" void kernel_launch(void* const* d_in, const int* in_sizes, int n_in,
                              void* d_out, int out_size, void* d_ws, size_t ws_size,
                              hipStream_t stream) {
    const float* x  = (const float*)d_in[0];
    const float* Wq = (const float*)d_in[1];
    const float* Wk = (const float*)d_in[2];
    const float* Wv = (const float*)d_in[3];
    const float* Wo = (const float*)d_in[4];

    short* wb  = (short*)d_ws;                 // 4 x 1M shorts (8 MB)
    short* Qw  = wb + (size_t)4 * 1048576;     // 8 MB (attn out aliases this)
    short* Kw  = Qw + (size_t)4194304;         // 8 MB
    short* Vtw = Kw + (size_t)4194304;         // 8 MB  (VtG[1024][4096])
    short* xb  = (short*)d_out;                // bf16 x lives in d_out[0:8MB]

    convert_kernel<<<dim3(2048, 5), 256, 0, stream>>>(x, Wq, Wk, Wv, Wo, xb, wb);
    gemm_qkv_kernel<<<dim3(32, 24), 256, 0, stream>>>(xb, wb, Qw, Kw, Vtw);
    attn_kernel<<<1024, 128, 0, stream>>>(Qw, Kw, Vtw, Qw);
    gemm_wo_kernel<<<dim3(32, 8), 256, 0, stream>>>(Qw, wb + (size_t)3 * 1048576, (float*)d_out);
}